// Round 17
// baseline (116.879 us; speedup 1.0000x reference)
//
#include <hip/hip_runtime.h>
#include <hip/hip_bf16.h>

#define LARGE_F 1e30f
#define LOG2E_F 1.4426950408889634f
#define LN2_F   0.6931471805599453f

constexpr int BB = 128;
constexpr int NN = 512;
constexpr int MM = 512;
constexpr int KK = 64;
// D layout: bf16, short index = 512*i + p (p = i+j). Row i spans [513i, 513i+511].
constexpr int PBATCH = 262656;              // shorts per batch (525,312 B)
constexpr size_t NEED = (size_t)BB * PBATCH * 2 + 4096;  // + prefetch overshoot slop

typedef __attribute__((ext_vector_type(8))) short short8;   // 8 bf16 (guide §3)
typedef __attribute__((ext_vector_type(4))) float f32x4;

// lane i <- lane i-1 via DPP wave_shr:1 (VALU). Lane 0 receives `bound`.
__device__ __forceinline__ float wave_shr1(float v, float bound) {
    const int r = __builtin_amdgcn_update_dpp(__float_as_int(bound), __float_as_int(v),
                                              0x138, 0xf, 0xf, false);
    return __int_as_float(r);
}

__device__ __forceinline__ unsigned pack_bf16(float a, float b) {
    __hip_bfloat16 ha = __float2bfloat16(a);
    __hip_bfloat16 hb = __float2bfloat16(b);
    return (unsigned)*(unsigned short*)&ha | ((unsigned)*(unsigned short*)&hb << 16);
}

// Raw-instruction transcendentals (v_exp_f32 / v_log_f32, ~1 ulp).
__device__ __forceinline__ float fast_exp2(float x) { return __builtin_amdgcn_exp2f(x); }
__device__ __forceinline__ float fast_log2(float x) { return __builtin_amdgcn_logf(x); }

// ---------------- Phase 1 (MFMA): D[i][p] = ||x_i - y_j||^2 * log2e (bf16).
// (unchanged from round 16)
__global__ __launch_bounds__(256, 2) void sdtw_dist(const float* __restrict__ x,
                                                    const float* __restrict__ y,
                                                    unsigned short* __restrict__ Dws) {
    __shared__ __align__(16) unsigned short xbf[128][88];
    __shared__ __align__(16) unsigned short ybf[128][88];
    __shared__ float x2s[128], y2s[128];
    __shared__ float xpart[128][2], ypart[128][2];
    unsigned short (*dt)[132] = (unsigned short (*)[132])(&xbf[0][0]);

    const int bid  = blockIdx.x;
    const int xcd  = bid & 7, sidx = bid >> 3;
    const int g    = sidx >> 4, tile = sidx & 15;
    const int b    = xcd + (g << 3);
    const int ti   = (tile >> 2) << 7, tj = (tile & 3) << 7;
    const int t    = threadIdx.x;

    const float* xb = x + ((size_t)b * NN + ti) * KK;
    const float* yb = y + ((size_t)b * MM + tj) * KK;

    {
        const int r = t >> 1, h = t & 1;
        const float* xr = xb + r * KK + h * 32;
        const float* yr = yb + r * KK + h * 32;
        float sx = 0.f, sy = 0.f;
        unsigned xu[16], yu[16];
#pragma unroll
        for (int q = 0; q < 8; ++q) {
            const float4 v = *(const float4*)(xr + 4 * q);
            sx = fmaf(v.x, v.x, fmaf(v.y, v.y, fmaf(v.z, v.z, fmaf(v.w, v.w, sx))));
            xu[2 * q]     = pack_bf16(v.x, v.y);
            xu[2 * q + 1] = pack_bf16(v.z, v.w);
            const float4 u = *(const float4*)(yr + 4 * q);
            sy = fmaf(u.x, u.x, fmaf(u.y, u.y, fmaf(u.z, u.z, fmaf(u.w, u.w, sy))));
            yu[2 * q]     = pack_bf16(u.x, u.y);
            yu[2 * q + 1] = pack_bf16(u.z, u.w);
        }
#pragma unroll
        for (int q = 0; q < 4; ++q) {
            *(uint4*)(&xbf[r][h * 32 + q * 8]) = make_uint4(xu[4*q], xu[4*q+1], xu[4*q+2], xu[4*q+3]);
            *(uint4*)(&ybf[r][h * 32 + q * 8]) = make_uint4(yu[4*q], yu[4*q+1], yu[4*q+2], yu[4*q+3]);
        }
        xpart[r][h] = sx; ypart[r][h] = sy;
    }
    __syncthreads();
    if (t < 128) x2s[t] = xpart[t][0] + xpart[t][1];
    else         y2s[t - 128] = ypart[t - 128][0] + ypart[t - 128][1];
    __syncthreads();

    const int w    = t >> 6, lane = t & 63;
    const int wr   = (w >> 1) << 6, wc = (w & 1) << 6;
    const int fr   = lane & 15;
    const int fk   = (lane >> 4) << 3;

    f32x4 acc[4][4] = {};
#pragma unroll
    for (int c = 0; c < 2; ++c) {
        short8 A[4], Bf[4];
#pragma unroll
        for (int a = 0; a < 4; ++a)
            A[a] = *(const short8*)(&xbf[wr + (a << 4) + fr][(c << 5) + fk]);
#pragma unroll
        for (int bb = 0; bb < 4; ++bb)
            Bf[bb] = *(const short8*)(&ybf[wc + (bb << 4) + fr][(c << 5) + fk]);
#pragma unroll
        for (int a = 0; a < 4; ++a)
#pragma unroll
            for (int bb = 0; bb < 4; ++bb)
                acc[a][bb] = __builtin_amdgcn_mfma_f32_16x16x32_bf16(
                    A[a], Bf[bb], acc[a][bb], 0, 0, 0);
    }
    __syncthreads();

    {
        const int er = (lane >> 4) << 2;
        const int ec = lane & 15;
#pragma unroll
        for (int a = 0; a < 4; ++a) {
#pragma unroll
            for (int bb = 0; bb < 4; ++bb) {
                const int lcol = wc + (bb << 4) + ec;
                const float yy = y2s[lcol];
#pragma unroll
                for (int reg = 0; reg < 4; ++reg) {
                    const int lrow = wr + (a << 4) + er + reg;
                    const float d = (x2s[lrow] + yy - 2.f * acc[a][bb][reg]) * LOG2E_F;
                    __hip_bfloat16 hh = __float2bfloat16(d);
                    dt[lrow][lcol] = *(unsigned short*)&hh;
                }
            }
        }
    }
    __syncthreads();

    {
        unsigned short* Dg = Dws + (size_t)b * PBATCH;
#pragma unroll 4
        for (int r = w; r < 128; r += 4) {
            const int gi = ti + r;
            const int base = 512 * gi + (gi + tj);
            Dg[base + lane]      = dt[r][lane];
            Dg[base + lane + 64] = dt[r][lane + 64];
        }
    }
}

// ---------------- Phase 2: ASYNC windowed band pipeline -- zero barriers in
// the main loop. Wave wv owns rows [64wv,64wv+63], processes its 36 useful
// bands (abs k = 4wv+c, c=0..35) free-running. Producer-consumer handoff via
// dedicated per-band LDS slots hnd[wave][band][16] (written once -> no reuse
// hazard) + per-wave progress counter: consumer band c spins until
// prog[wv-1] >= min(c+5,36) (needs producer local slots c+3, c+4). Producer
// orders data->flag with lgkmcnt(0). Slots past the producer window (c>31)
// feed only provably-invalid cells -> LARGE. Depth-2 band prefetch.
__global__ __launch_bounds__(512, 1) void sdtw_dp(const unsigned short* __restrict__ Dws,
                                                  float* __restrict__ out) {
    __shared__ __align__(16) float hnd[8][36][16];   // 18,432 B
    __shared__ int prog[8];
    const int b    = blockIdx.x;
    const int tid  = threadIdx.x;        // row
    const int lane = tid & 63;
    const int wv   = tid >> 6;
    const int k0   = wv << 2;
    const int pw   = (wv > 0) ? (wv - 1) : 0;

    if (tid < 8) prog[tid] = 0;
    __syncthreads();

    const char* Dbase = (const char*)Dws;
    unsigned off = (unsigned)b * 525312u + (unsigned)tid * 1024u + ((unsigned)k0 << 5);

    float cur = LARGE_F;                     // R_{p-1}[tid]
    float nw  = (tid == 0) ? 0.f : LARGE_F;  // R_{p-2}[tid-1]; corner (0,0)=0
    float res = 0.f;
    float hband_prev = LARGE_F;
    const bool haveup = (wv > 0);
    const bool l0     = (lane == 0);

    uint4 cb[2][2];                          // depth-2 band prefetch
    cb[0][0] = *(const uint4*)(Dbase + off);
    cb[0][1] = *(const uint4*)(Dbase + off + 16);
    cb[1][0] = *(const uint4*)(Dbase + off + 32);
    cb[1][1] = *(const uint4*)(Dbase + off + 48);
    off += 64;

    volatile int* vp = (volatile int*)prog;

#pragma unroll 1
    for (int ci = 0; ci < 18; ++ci) {
#pragma unroll
        for (int half = 0; half < 2; ++half) {
            const int c = 2 * ci + half;     // local band index 0..35
            // Unpack current band, then refill this buffer with band c+2.
            const unsigned q[8] = {cb[half][0].x, cb[half][0].y, cb[half][0].z,
                                   cb[half][0].w, cb[half][1].x, cb[half][1].y,
                                   cb[half][1].z, cb[half][1].w};
            float d[16];
#pragma unroll
            for (int u = 0; u < 16; ++u) {
                const unsigned w_ = q[u >> 1];
                d[u] = __uint_as_float((u & 1) ? (w_ & 0xffff0000u) : (w_ << 16));
            }
            cb[half][0] = *(const uint4*)(Dbase + off);   // overshoot -> slop
            cb[half][1] = *(const uint4*)(Dbase + off + 16);
            off += 32;
            __builtin_amdgcn_sched_barrier(0);

            // Flow control: wait for producer slots c+3, c+4.
            if (haveup) {
                const int target = (c + 5 < 36) ? (c + 5) : 36;
                while (vp[pw] < target) { asm volatile("s_sleep 2"); }
            }
            __builtin_amdgcn_sched_barrier(0);
            asm volatile("" ::: "memory");

            if (c == 0 && haveup) hband_prev = hnd[pw][3][15];
            const float hband = (haveup && c <= 31) ? hnd[pw][c + 4][lane & 15]
                                                    : LARGE_F;
            float h[16];
#pragma unroll
            for (int u = 0; u < 16; ++u) {
                const float nvec = wave_shr1(cur, LARGE_F);
                const float hu = __int_as_float(__builtin_amdgcn_readlane(
                    __float_as_int((u == 0) ? hband_prev : hband),
                    (u == 0) ? 15 : (u - 1)));
                const float n  = (haveup && l0) ? hu : nvec;
                const float mn = fminf(fminf(cur, n), nw);
                const float mx = fmaxf(fmaxf(cur, n), nw);
                const float md = __builtin_amdgcn_fmed3f(cur, n, nw);
                const float sm = mn - fast_log2(1.f + fast_exp2(mn - md) + fast_exp2(mn - mx));
                const float newc = d[u] + sm;
                h[u] = newc;
                nw = n; cur = newc;
            }
            hband_prev = hband;
            if (c == 35) res = h[14];        // abs band 63 only for wv==7 (tid 511)
            if (lane == 63) {                // export + release
                *(float4*)(&hnd[wv][c][0])  = make_float4(h[0], h[1], h[2], h[3]);
                *(float4*)(&hnd[wv][c][4])  = make_float4(h[4], h[5], h[6], h[7]);
                *(float4*)(&hnd[wv][c][8])  = make_float4(h[8], h[9], h[10], h[11]);
                *(float4*)(&hnd[wv][c][12]) = make_float4(h[12], h[13], h[14], h[15]);
                asm volatile("s_waitcnt lgkmcnt(0)" ::: "memory");
                *(volatile int*)&prog[wv] = c + 1;
            }
        }
    }
    if (tid == 511) out[b] = res * LN2_F;
}

// ---------------- Fallback (only if ws too small): fused, correct, slow.
__global__ __launch_bounds__(512) void sdtw_fused_naive(const float* __restrict__ x,
                                                        const float* __restrict__ y,
                                                        float* __restrict__ out) {
    __shared__ float rbuf[3][NN];
    __shared__ float y2s[MM];
    const int b = blockIdx.x;
    const int i = threadIdx.x;

    const float* xrow  = x + ((size_t)b * NN + i) * KK;
    const float* ybase = y + (size_t)b * MM * KK;

    float xr[KK];
    float x2 = 0.f;
#pragma unroll
    for (int k = 0; k < KK; k += 4) {
        const float4 v = *(const float4*)(xrow + k);
        xr[k] = v.x; xr[k + 1] = v.y; xr[k + 2] = v.z; xr[k + 3] = v.w;
        x2 = fmaf(v.x, v.x, fmaf(v.y, v.y, fmaf(v.z, v.z, fmaf(v.w, v.w, x2))));
    }
    {
        const float* yrow = ybase + (size_t)i * KK;
        float s = 0.f;
#pragma unroll
        for (int k = 0; k < KK; k += 4) {
            const float4 v = *(const float4*)(yrow + k);
            s = fmaf(v.x, v.x, s); s = fmaf(v.y, v.y, s);
            s = fmaf(v.z, v.z, s); s = fmaf(v.w, v.w, s);
        }
        y2s[i] = s;
    }
    rbuf[0][i] = LARGE_F;
    rbuf[1][i] = LARGE_F;
    rbuf[2][i] = LARGE_F;

    float* row_w  = rbuf[0];
    float* row_p  = rbuf[2];
    float* row_p2 = rbuf[1];
    __syncthreads();

    float cur = LARGE_F;
    for (int p = 0; p < NN + MM - 1; ++p) {
        const int j0 = p - i;
        const bool valid = (j0 >= 0) && (j0 < MM);
        float dg = 0.f;
        if (valid) {
            const float* yrow = ybase + (size_t)j0 * KK;
            float dot = 0.f;
#pragma unroll
            for (int k = 0; k < KK; k += 4) {
                const float4 v = *(const float4*)(yrow + k);
                dot = fmaf(xr[k], v.x, dot);
                dot = fmaf(xr[k + 1], v.y, dot);
                dot = fmaf(xr[k + 2], v.z, dot);
                dot = fmaf(xr[k + 3], v.w, dot);
            }
            dg = x2 + y2s[j0] - 2.f * dot;
        }
        const float r_w  = row_p[i];
        const float r_n  = (i > 0) ? row_p[i - 1] : LARGE_F;
        const float r_nw = (i > 0) ? row_p2[i - 1] : ((p == 0) ? 0.f : LARGE_F);

        const float m = fminf(fminf(r_nw, r_n), r_w);
        const float s = __expf(m - r_nw) + __expf(m - r_n) + __expf(m - r_w);
        const float softmin = m - __logf(s);

        cur = valid ? (dg + softmin) : LARGE_F;
        row_w[i] = cur;
        __syncthreads();

        float* tmp = row_w;
        row_w = row_p2; row_p2 = row_p; row_p = tmp;
    }
    if (i == NN - 1) out[b] = cur;
}

extern "C" void kernel_launch(void* const* d_in, const int* in_sizes, int n_in,
                              void* d_out, int out_size, void* d_ws, size_t ws_size,
                              hipStream_t stream) {
    const float* x = (const float*)d_in[0];
    const float* y = (const float*)d_in[1];
    float* out = (float*)d_out;

    if (ws_size >= NEED) {   // 67,244,032 B
        unsigned short* Dws = (unsigned short*)d_ws;
        sdtw_dist<<<dim3(2048), 256, 0, stream>>>(x, y, Dws);
        sdtw_dp<<<dim3(BB), 512, 0, stream>>>(Dws, out);
    } else {
        sdtw_fused_naive<<<dim3(BB), 512, 0, stream>>>(x, y, out);
    }
}

// Round 18
// 110.293 us; speedup vs baseline: 1.0597x; 1.0597x over previous
//
#include <hip/hip_runtime.h>
#include <hip/hip_bf16.h>

#define LARGE_F 1e30f
#define LOG2E_F 1.4426950408889634f
#define LN2_F   0.6931471805599453f

constexpr int BB = 128;
constexpr int NN = 512;
constexpr int MM = 512;
constexpr int KK = 64;
// D layout: bf16, short index = 512*i + p (p = i+j). Row i spans [513i, 513i+511].
constexpr int PBATCH = 262656;              // shorts per batch (525,312 B)
constexpr int EXPN   = 65536;               // floats per export array (128*512)
constexpr size_t EXP_OFF = 67239936;        // bytes (= 128*PBATCH*2), 16B-aligned
constexpr size_t NEED = EXP_OFF + 4 * (size_t)EXPN * 4;   // 68,288,512 B

typedef __attribute__((ext_vector_type(8))) short short8;   // 8 bf16 (guide §3)
typedef __attribute__((ext_vector_type(4))) float f32x4;

// lane i <- lane i-1 via DPP wave_shr:1 (VALU). Lane 0 receives `bound`.
__device__ __forceinline__ float wave_shr1(float v, float bound) {
    const int r = __builtin_amdgcn_update_dpp(__float_as_int(bound), __float_as_int(v),
                                              0x138, 0xf, 0xf, false);
    return __int_as_float(r);
}

__device__ __forceinline__ unsigned pack_bf16(float a, float b) {
    __hip_bfloat16 ha = __float2bfloat16(a);
    __hip_bfloat16 hb = __float2bfloat16(b);
    return (unsigned)*(unsigned short*)&ha | ((unsigned)*(unsigned short*)&hb << 16);
}

// Raw-instruction transcendentals (v_exp_f32 / v_log_f32, ~1 ulp).
__device__ __forceinline__ float fast_exp2(float x) { return __builtin_amdgcn_exp2f(x); }
__device__ __forceinline__ float fast_log2(float x) { return __builtin_amdgcn_logf(x); }

// ---------------- Phase 1 (MFMA): D[i][p] = ||x_i - y_j||^2 * log2e (bf16).
// (unchanged; proven rounds 14-17)
__global__ __launch_bounds__(256, 2) void sdtw_dist(const float* __restrict__ x,
                                                    const float* __restrict__ y,
                                                    unsigned short* __restrict__ Dws) {
    __shared__ __align__(16) unsigned short xbf[128][88];
    __shared__ __align__(16) unsigned short ybf[128][88];
    __shared__ float x2s[128], y2s[128];
    __shared__ float xpart[128][2], ypart[128][2];
    unsigned short (*dt)[132] = (unsigned short (*)[132])(&xbf[0][0]);

    const int bid  = blockIdx.x;
    const int xcd  = bid & 7, sidx = bid >> 3;
    const int g    = sidx >> 4, tile = sidx & 15;
    const int b    = xcd + (g << 3);
    const int ti   = (tile >> 2) << 7, tj = (tile & 3) << 7;
    const int t    = threadIdx.x;

    const float* xb = x + ((size_t)b * NN + ti) * KK;
    const float* yb = y + ((size_t)b * MM + tj) * KK;

    {
        const int r = t >> 1, h = t & 1;
        const float* xr = xb + r * KK + h * 32;
        const float* yr = yb + r * KK + h * 32;
        float sx = 0.f, sy = 0.f;
        unsigned xu[16], yu[16];
#pragma unroll
        for (int q = 0; q < 8; ++q) {
            const float4 v = *(const float4*)(xr + 4 * q);
            sx = fmaf(v.x, v.x, fmaf(v.y, v.y, fmaf(v.z, v.z, fmaf(v.w, v.w, sx))));
            xu[2 * q]     = pack_bf16(v.x, v.y);
            xu[2 * q + 1] = pack_bf16(v.z, v.w);
            const float4 u = *(const float4*)(yr + 4 * q);
            sy = fmaf(u.x, u.x, fmaf(u.y, u.y, fmaf(u.z, u.z, fmaf(u.w, u.w, sy))));
            yu[2 * q]     = pack_bf16(u.x, u.y);
            yu[2 * q + 1] = pack_bf16(u.z, u.w);
        }
#pragma unroll
        for (int q = 0; q < 4; ++q) {
            *(uint4*)(&xbf[r][h * 32 + q * 8]) = make_uint4(xu[4*q], xu[4*q+1], xu[4*q+2], xu[4*q+3]);
            *(uint4*)(&ybf[r][h * 32 + q * 8]) = make_uint4(yu[4*q], yu[4*q+1], yu[4*q+2], yu[4*q+3]);
        }
        xpart[r][h] = sx; ypart[r][h] = sy;
    }
    __syncthreads();
    if (t < 128) x2s[t] = xpart[t][0] + xpart[t][1];
    else         y2s[t - 128] = ypart[t - 128][0] + ypart[t - 128][1];
    __syncthreads();

    const int w    = t >> 6, lane = t & 63;
    const int wr   = (w >> 1) << 6, wc = (w & 1) << 6;
    const int fr   = lane & 15;
    const int fk   = (lane >> 4) << 3;

    f32x4 acc[4][4] = {};
#pragma unroll
    for (int c = 0; c < 2; ++c) {
        short8 A[4], Bf[4];
#pragma unroll
        for (int a = 0; a < 4; ++a)
            A[a] = *(const short8*)(&xbf[wr + (a << 4) + fr][(c << 5) + fk]);
#pragma unroll
        for (int bb = 0; bb < 4; ++bb)
            Bf[bb] = *(const short8*)(&ybf[wc + (bb << 4) + fr][(c << 5) + fk]);
#pragma unroll
        for (int a = 0; a < 4; ++a)
#pragma unroll
            for (int bb = 0; bb < 4; ++bb)
                acc[a][bb] = __builtin_amdgcn_mfma_f32_16x16x32_bf16(
                    A[a], Bf[bb], acc[a][bb], 0, 0, 0);
    }
    __syncthreads();

    {
        const int er = (lane >> 4) << 2;
        const int ec = lane & 15;
#pragma unroll
        for (int a = 0; a < 4; ++a) {
#pragma unroll
            for (int bb = 0; bb < 4; ++bb) {
                const int lcol = wc + (bb << 4) + ec;
                const float yy = y2s[lcol];
#pragma unroll
                for (int reg = 0; reg < 4; ++reg) {
                    const int lrow = wr + (a << 4) + er + reg;
                    const float d = (x2s[lrow] + yy - 2.f * acc[a][bb][reg]) * LOG2E_F;
                    __hip_bfloat16 hh = __float2bfloat16(d);
                    dt[lrow][lcol] = *(unsigned short*)&hh;
                }
            }
        }
    }
    __syncthreads();

    {
        unsigned short* Dg = Dws + (size_t)b * PBATCH;
#pragma unroll 4
        for (int r = w; r < 128; r += 4) {
            const int gi = ti + r;
            const int base = 512 * gi + (gi + tj);
            Dg[base + lane]      = dt[r][lane];
            Dg[base + lane + 64] = dt[r][lane + 64];
        }
    }
}

// ---------------- Phase 2: TRIANGLE DP (fwd & bwd), 256 blocks = 2 per batch.
// blk = 2*batch + dir. dir 0: forward DP on diagonals 0..511 (r16 structure,
// window [4wv, 31] -> 39 epochs). dir 1: identical DP on reversed coordinates
// (i'=511-i, j'=511-j) reading Dws in descending-p order (16 ushort loads).
// Each exports its diag-511 and diag-510 row values (f32) for the combine.
__global__ __launch_bounds__(512, 1) void sdtw_dp_tri(const unsigned short* __restrict__ Dws,
                                                      float* __restrict__ exps) {
    __shared__ __align__(16) float hnd[3][8][16];
    const int blk   = blockIdx.x;
    const int batch = blk >> 1, dir = blk & 1;
    const int tid   = threadIdx.x;       // row (in this direction's coords)
    const int lane  = tid & 63;
    const int wv    = tid >> 6;
    const int k0    = wv << 2;

    if (tid < 384) ((float*)hnd)[tid] = LARGE_F;
    __syncthreads();

    const unsigned short* Dp = Dws + (size_t)batch * PBATCH;
    const char* Dbase = (const char*)Dp;

    float cur = LARGE_F;                     // R_{p-1}[tid]
    float nw  = (tid == 0) ? 0.f : LARGE_F;  // corner (0,0)
    float hband_prev = LARGE_F;
    const bool haveup = (wv > 0);
    const bool l0     = (lane == 0);
    float r510 = LARGE_F, r511 = LARGE_F;

    // Prologue: load band k0.
    unsigned off = (unsigned)tid * 1024u + ((unsigned)k0 << 5);
    uint4 c0, c1;
    unsigned short nb[16];
    int base = 0;
    if (dir == 0) {
        c0 = *(const uint4*)(Dbase + off);
        c1 = *(const uint4*)(Dbase + off + 16);
        off += 32;
    } else {
        // bwd thread tid owns original row 511-tid; band k covers original
        // p = 1022-16k-u (u=0..15): contiguous descending shorts, in-bounds.
        base = 512 * (511 - tid) + 1022 - (k0 << 4);
#pragma unroll
        for (int u = 0; u < 16; ++u) nb[u] = Dp[base - u];
        base -= 16;
    }

    int m0 = 0, m1 = 2;                      // e%3, (e-1)%3
#pragma unroll 1
    for (int e = 0; e < 39; ++e) {
        const int k = e - wv;
        if (k >= k0 && k <= 31) {
            float d[16];
            if (dir == 0) {
                const unsigned q[8] = {c0.x, c0.y, c0.z, c0.w, c1.x, c1.y, c1.z, c1.w};
#pragma unroll
                for (int u = 0; u < 16; ++u) {
                    const unsigned w_ = q[u >> 1];
                    d[u] = __uint_as_float((u & 1) ? (w_ & 0xffff0000u) : (w_ << 16));
                }
                c0 = *(const uint4*)(Dbase + off);   // band 32 overshoot in-bounds
                c1 = *(const uint4*)(Dbase + off + 16);
                off += 32;
            } else {
#pragma unroll
                for (int u = 0; u < 16; ++u)
                    d[u] = __uint_as_float((unsigned)nb[u] << 16);
#pragma unroll
                for (int u = 0; u < 16; ++u) nb[u] = Dp[base - u];  // prefetch k+1
                base -= 16;
            }
            __builtin_amdgcn_sched_barrier(0);       // pin loads before compute

            if (k == k0 && haveup) {                 // window entry boundary
                const int m2 = 3 - m0 - m1;
                hband_prev = hnd[m2][wv - 1][15];
            }
            const float hband = haveup ? hnd[m1][wv - 1][lane & 15] : LARGE_F;
            float h[16];
#pragma unroll
            for (int u = 0; u < 16; ++u) {
                const float nvec = wave_shr1(cur, LARGE_F);
                const float hu = __int_as_float(__builtin_amdgcn_readlane(
                    __float_as_int((u == 0) ? hband_prev : hband),
                    (u == 0) ? 15 : (u - 1)));
                const float n  = (haveup && l0) ? hu : nvec;
                const float mn = fminf(fminf(cur, n), nw);
                const float mx = fmaxf(fmaxf(cur, n), nw);
                const float md = __builtin_amdgcn_fmed3f(cur, n, nw);
                const float sm = mn - fast_log2(1.f + fast_exp2(mn - md) + fast_exp2(mn - mx));
                const float newc = d[u] + sm;
                h[u] = newc;
                nw = n; cur = newc;
            }
            hband_prev = hband;
            if (k == 31) { r510 = h[14]; r511 = h[15]; }   // p=510, p=511
            if (lane == 63) {
                *(float4*)(&hnd[m0][wv][0])  = make_float4(h[0], h[1], h[2], h[3]);
                *(float4*)(&hnd[m0][wv][4])  = make_float4(h[4], h[5], h[6], h[7]);
                *(float4*)(&hnd[m0][wv][8])  = make_float4(h[8], h[9], h[10], h[11]);
                *(float4*)(&hnd[m0][wv][12]) = make_float4(h[12], h[13], h[14], h[15]);
            }
        }
        asm volatile("s_waitcnt lgkmcnt(0)" ::: "memory");
        __builtin_amdgcn_s_barrier();        // raw: vmcnt NOT drained
        m0 = (m0 == 2) ? 0 : m0 + 1;
        m1 = (m1 == 2) ? 0 : m1 + 1;
    }
    // exports: arrays [0]=Rf511 [1]=Rf510 [2]=Rb511 [3]=Rb510, each [batch][row]
    exps[((dir << 1) + 0) * EXPN + (batch << 9) + tid] = r511;
    exps[((dir << 1) + 1) * EXPN + (batch << 9) + tid] = r510;
}

// ---------------- Phase 3: combine. Every monotone path crosses diag 511 once
// (term1, D'-corrected) or jumps 510->512 (term2). Max-subtracted log2sumexp.
__global__ __launch_bounds__(512) void sdtw_combine(const unsigned short* __restrict__ Dws,
                                                    const float* __restrict__ exps,
                                                    float* __restrict__ out) {
    __shared__ float red[8];
    const int b = blockIdx.x, i = threadIdx.x;
    const int lane = i & 63, wv = i >> 6;

    const float rf511 = exps[0 * EXPN + (b << 9) + i];
    const float rf510 = exps[1 * EXPN + (b << 9) + i];
    const float rb511 = exps[2 * EXPN + (b << 9) + (511 - i)];
    const float rb510 = (i < 511) ? exps[3 * EXPN + (b << 9) + (510 - i)] : 0.f;
    const unsigned short dsh = Dws[(size_t)b * PBATCH + (i << 9) + 511];  // D'(i,511-i)
    const float d511 = __uint_as_float((unsigned)dsh << 16);

    const float t1 = d511 - rf511 - rb511;                  // visit diag 511
    const float t2 = (i < 511) ? (-rf510 - rb510) : -LARGE_F;  // jump 510->512

    float m = fmaxf(t1, t2);
#pragma unroll
    for (int s_ = 1; s_ < 64; s_ <<= 1) m = fmaxf(m, __shfl_xor(m, s_));
    if (lane == 0) red[wv] = m;
    __syncthreads();
    float M = red[0];
#pragma unroll
    for (int w_ = 1; w_ < 8; ++w_) M = fmaxf(M, red[w_]);
    __syncthreads();

    float s = fast_exp2(t1 - M) + ((i < 511) ? fast_exp2(t2 - M) : 0.f);
#pragma unroll
    for (int s_ = 1; s_ < 64; s_ <<= 1) s += __shfl_xor(s, s_);
    if (lane == 0) red[wv] = s;
    __syncthreads();
    if (i == 0) {
        float S = red[0];
#pragma unroll
        for (int w_ = 1; w_ < 8; ++w_) S += red[w_];
        out[b] = -(M + fast_log2(S)) * LN2_F;
    }
}

// ---------------- Fallback (only if ws too small): fused, correct, slow.
__global__ __launch_bounds__(512) void sdtw_fused_naive(const float* __restrict__ x,
                                                        const float* __restrict__ y,
                                                        float* __restrict__ out) {
    __shared__ float rbuf[3][NN];
    __shared__ float y2s[MM];
    const int b = blockIdx.x;
    const int i = threadIdx.x;

    const float* xrow  = x + ((size_t)b * NN + i) * KK;
    const float* ybase = y + (size_t)b * MM * KK;

    float xr[KK];
    float x2 = 0.f;
#pragma unroll
    for (int k = 0; k < KK; k += 4) {
        const float4 v = *(const float4*)(xrow + k);
        xr[k] = v.x; xr[k + 1] = v.y; xr[k + 2] = v.z; xr[k + 3] = v.w;
        x2 = fmaf(v.x, v.x, fmaf(v.y, v.y, fmaf(v.z, v.z, fmaf(v.w, v.w, x2))));
    }
    {
        const float* yrow = ybase + (size_t)i * KK;
        float s = 0.f;
#pragma unroll
        for (int k = 0; k < KK; k += 4) {
            const float4 v = *(const float4*)(yrow + k);
            s = fmaf(v.x, v.x, s); s = fmaf(v.y, v.y, s);
            s = fmaf(v.z, v.z, s); s = fmaf(v.w, v.w, s);
        }
        y2s[i] = s;
    }
    rbuf[0][i] = LARGE_F;
    rbuf[1][i] = LARGE_F;
    rbuf[2][i] = LARGE_F;

    float* row_w  = rbuf[0];
    float* row_p  = rbuf[2];
    float* row_p2 = rbuf[1];
    __syncthreads();

    float cur = LARGE_F;
    for (int p = 0; p < NN + MM - 1; ++p) {
        const int j0 = p - i;
        const bool valid = (j0 >= 0) && (j0 < MM);
        float dg = 0.f;
        if (valid) {
            const float* yrow = ybase + (size_t)j0 * KK;
            float dot = 0.f;
#pragma unroll
            for (int k = 0; k < KK; k += 4) {
                const float4 v = *(const float4*)(yrow + k);
                dot = fmaf(xr[k], v.x, dot);
                dot = fmaf(xr[k + 1], v.y, dot);
                dot = fmaf(xr[k + 2], v.z, dot);
                dot = fmaf(xr[k + 3], v.w, dot);
            }
            dg = x2 + y2s[j0] - 2.f * dot;
        }
        const float r_w  = row_p[i];
        const float r_n  = (i > 0) ? row_p[i - 1] : LARGE_F;
        const float r_nw = (i > 0) ? row_p2[i - 1] : ((p == 0) ? 0.f : LARGE_F);

        const float m = fminf(fminf(r_nw, r_n), r_w);
        const float s = __expf(m - r_nw) + __expf(m - r_n) + __expf(m - r_w);
        const float softmin = m - __logf(s);

        cur = valid ? (dg + softmin) : LARGE_F;
        row_w[i] = cur;
        __syncthreads();

        float* tmp = row_w;
        row_w = row_p2; row_p2 = row_p; row_p = tmp;
    }
    if (i == NN - 1) out[b] = cur;
}

extern "C" void kernel_launch(void* const* d_in, const int* in_sizes, int n_in,
                              void* d_out, int out_size, void* d_ws, size_t ws_size,
                              hipStream_t stream) {
    const float* x = (const float*)d_in[0];
    const float* y = (const float*)d_in[1];
    float* out = (float*)d_out;

    if (ws_size >= NEED) {   // 68,288,512 B
        unsigned short* Dws = (unsigned short*)d_ws;
        float* exps = (float*)((char*)d_ws + EXP_OFF);
        sdtw_dist<<<dim3(2048), 256, 0, stream>>>(x, y, Dws);
        sdtw_dp_tri<<<dim3(256), 512, 0, stream>>>(Dws, exps);
        sdtw_combine<<<dim3(BB), 512, 0, stream>>>(Dws, exps, out);
    } else {
        sdtw_fused_naive<<<dim3(BB), 512, 0, stream>>>(x, y, out);
    }
}

// Round 19
// 95.410 us; speedup vs baseline: 1.2250x; 1.1560x over previous
//
#include <hip/hip_runtime.h>
#include <hip/hip_bf16.h>

#define LARGE_F 1e30f
#define LOG2E_F 1.4426950408889634f
#define LN2_F   0.6931471805599453f

constexpr int BB = 128;
constexpr int NN = 512;
constexpr int MM = 512;
constexpr int KK = 64;
// D layout: bf16, short index = 512*i + p (p = i+j). Row i spans [513i, 513i+511].
constexpr int PBATCH = 262656;              // shorts per batch (525,312 B)
constexpr int EXPN   = 65536;               // floats per export array (128*512)
constexpr size_t EXP_OFF = 67239936;        // bytes (= 128*PBATCH*2), 16B-aligned
constexpr size_t NEED = EXP_OFF + 4 * (size_t)EXPN * 4;   // 68,288,512 B

typedef __attribute__((ext_vector_type(8))) short short8;   // 8 bf16 (guide §3)
typedef __attribute__((ext_vector_type(4))) float f32x4;

// lane i <- lane i-1 via DPP wave_shr:1 (VALU). Lane 0 receives `bound`.
__device__ __forceinline__ float wave_shr1(float v, float bound) {
    const int r = __builtin_amdgcn_update_dpp(__float_as_int(bound), __float_as_int(v),
                                              0x138, 0xf, 0xf, false);
    return __int_as_float(r);
}

__device__ __forceinline__ unsigned pack_bf16(float a, float b) {
    __hip_bfloat16 ha = __float2bfloat16(a);
    __hip_bfloat16 hb = __float2bfloat16(b);
    return (unsigned)*(unsigned short*)&ha | ((unsigned)*(unsigned short*)&hb << 16);
}

// Raw-instruction transcendentals (v_exp_f32 / v_log_f32, ~1 ulp).
__device__ __forceinline__ float fast_exp2(float x) { return __builtin_amdgcn_exp2f(x); }
__device__ __forceinline__ float fast_log2(float x) { return __builtin_amdgcn_logf(x); }

// ---------------- Phase 1 (MFMA): D[i][p] = ||x_i - y_j||^2 * log2e (bf16).
// (unchanged; proven rounds 14-18)
__global__ __launch_bounds__(256, 2) void sdtw_dist(const float* __restrict__ x,
                                                    const float* __restrict__ y,
                                                    unsigned short* __restrict__ Dws) {
    __shared__ __align__(16) unsigned short xbf[128][88];
    __shared__ __align__(16) unsigned short ybf[128][88];
    __shared__ float x2s[128], y2s[128];
    __shared__ float xpart[128][2], ypart[128][2];
    unsigned short (*dt)[132] = (unsigned short (*)[132])(&xbf[0][0]);

    const int bid  = blockIdx.x;
    const int xcd  = bid & 7, sidx = bid >> 3;
    const int g    = sidx >> 4, tile = sidx & 15;
    const int b    = xcd + (g << 3);
    const int ti   = (tile >> 2) << 7, tj = (tile & 3) << 7;
    const int t    = threadIdx.x;

    const float* xb = x + ((size_t)b * NN + ti) * KK;
    const float* yb = y + ((size_t)b * MM + tj) * KK;

    {
        const int r = t >> 1, h = t & 1;
        const float* xr = xb + r * KK + h * 32;
        const float* yr = yb + r * KK + h * 32;
        float sx = 0.f, sy = 0.f;
        unsigned xu[16], yu[16];
#pragma unroll
        for (int q = 0; q < 8; ++q) {
            const float4 v = *(const float4*)(xr + 4 * q);
            sx = fmaf(v.x, v.x, fmaf(v.y, v.y, fmaf(v.z, v.z, fmaf(v.w, v.w, sx))));
            xu[2 * q]     = pack_bf16(v.x, v.y);
            xu[2 * q + 1] = pack_bf16(v.z, v.w);
            const float4 u = *(const float4*)(yr + 4 * q);
            sy = fmaf(u.x, u.x, fmaf(u.y, u.y, fmaf(u.z, u.z, fmaf(u.w, u.w, sy))));
            yu[2 * q]     = pack_bf16(u.x, u.y);
            yu[2 * q + 1] = pack_bf16(u.z, u.w);
        }
#pragma unroll
        for (int q = 0; q < 4; ++q) {
            *(uint4*)(&xbf[r][h * 32 + q * 8]) = make_uint4(xu[4*q], xu[4*q+1], xu[4*q+2], xu[4*q+3]);
            *(uint4*)(&ybf[r][h * 32 + q * 8]) = make_uint4(yu[4*q], yu[4*q+1], yu[4*q+2], yu[4*q+3]);
        }
        xpart[r][h] = sx; ypart[r][h] = sy;
    }
    __syncthreads();
    if (t < 128) x2s[t] = xpart[t][0] + xpart[t][1];
    else         y2s[t - 128] = ypart[t - 128][0] + ypart[t - 128][1];
    __syncthreads();

    const int w    = t >> 6, lane = t & 63;
    const int wr   = (w >> 1) << 6, wc = (w & 1) << 6;
    const int fr   = lane & 15;
    const int fk   = (lane >> 4) << 3;

    f32x4 acc[4][4] = {};
#pragma unroll
    for (int c = 0; c < 2; ++c) {
        short8 A[4], Bf[4];
#pragma unroll
        for (int a = 0; a < 4; ++a)
            A[a] = *(const short8*)(&xbf[wr + (a << 4) + fr][(c << 5) + fk]);
#pragma unroll
        for (int bb = 0; bb < 4; ++bb)
            Bf[bb] = *(const short8*)(&ybf[wc + (bb << 4) + fr][(c << 5) + fk]);
#pragma unroll
        for (int a = 0; a < 4; ++a)
#pragma unroll
            for (int bb = 0; bb < 4; ++bb)
                acc[a][bb] = __builtin_amdgcn_mfma_f32_16x16x32_bf16(
                    A[a], Bf[bb], acc[a][bb], 0, 0, 0);
    }
    __syncthreads();

    {
        const int er = (lane >> 4) << 2;
        const int ec = lane & 15;
#pragma unroll
        for (int a = 0; a < 4; ++a) {
#pragma unroll
            for (int bb = 0; bb < 4; ++bb) {
                const int lcol = wc + (bb << 4) + ec;
                const float yy = y2s[lcol];
#pragma unroll
                for (int reg = 0; reg < 4; ++reg) {
                    const int lrow = wr + (a << 4) + er + reg;
                    const float d = (x2s[lrow] + yy - 2.f * acc[a][bb][reg]) * LOG2E_F;
                    __hip_bfloat16 hh = __float2bfloat16(d);
                    dt[lrow][lcol] = *(unsigned short*)&hh;
                }
            }
        }
    }
    __syncthreads();

    {
        unsigned short* Dg = Dws + (size_t)b * PBATCH;
#pragma unroll 4
        for (int r = w; r < 128; r += 4) {
            const int gi = ti + r;
            const int base = 512 * gi + (gi + tj);
            Dg[base + lane]      = dt[r][lane];
            Dg[base + lane + 64] = dt[r][lane + 64];
        }
    }
}

// ---------------- Phase 2: TRIANGLE DP (fwd & bwd), 256 blocks = 2 per batch.
// dir 0: forward DP on diagonals 0..511 (r16 structure, window [4wv,31], 39
// epochs). dir 1: same DP on reversed coords. Round-19 fix: bwd reads its 16
// contiguous descending shorts via 1 u32 + 2 uint4 ALIGNED loads (s0 == 7 mod
// 8, a0 = s0-7 is 16B-aligned) + static extraction -- was 16 scalar ushort
// loads = 8x the L1 line-lookups, which made bwd the kernel's critical path.
__global__ __launch_bounds__(512, 1) void sdtw_dp_tri(const unsigned short* __restrict__ Dws,
                                                      float* __restrict__ exps) {
    __shared__ __align__(16) float hnd[3][8][16];
    const int blk   = blockIdx.x;
    const int batch = blk >> 1, dir = blk & 1;
    const int tid   = threadIdx.x;       // row (in this direction's coords)
    const int lane  = tid & 63;
    const int wv    = tid >> 6;
    const int k0    = wv << 2;

    if (tid < 384) ((float*)hnd)[tid] = LARGE_F;
    __syncthreads();

    const unsigned short* Dp = Dws + (size_t)batch * PBATCH;
    const char* Dbase = (const char*)Dp;

    float cur = LARGE_F;                     // R_{p-1}[tid]
    float nw  = (tid == 0) ? 0.f : LARGE_F;  // corner (0,0)
    float hband_prev = LARGE_F;
    const bool haveup = (wv > 0);
    const bool l0     = (lane == 0);
    float r510 = LARGE_F, r511 = LARGE_F;

    // Prologue: load band k0.
    unsigned off = (unsigned)tid * 1024u + ((unsigned)k0 << 5);
    uint4 c0, c1;            // fwd band regs
    unsigned B0; uint4 B1, B2;   // bwd band regs (shorts a0+6..7, +8..15, +16..23)
    int a0 = 0;
    if (dir == 0) {
        c0 = *(const uint4*)(Dbase + off);
        c1 = *(const uint4*)(Dbase + off + 16);
        off += 32;
    } else {
        // bwd thread tid owns orig row r=511-tid; band k needs shorts
        // [s0, s0+15], s0 = 512r + 1007 - 16k (d[u] = shorts[s0+15-u]).
        // a0 = s0-7 is 16B-aligned; window read as u32@a0+6 + uint4@a0+8,+16.
        a0 = 512 * (511 - tid) + 1000 - (k0 << 4);
        B0 = *(const unsigned*)(Dp + a0 + 6);
        B1 = *(const uint4*)(Dp + a0 + 8);
        B2 = *(const uint4*)(Dp + a0 + 16);
        a0 -= 16;
    }

    int m0 = 0, m1 = 2;                      // e%3, (e-1)%3
#pragma unroll 1
    for (int e = 0; e < 39; ++e) {
        const int k = e - wv;
        if (k >= k0 && k <= 31) {
            float d[16];
            if (dir == 0) {
                const unsigned q[8] = {c0.x, c0.y, c0.z, c0.w, c1.x, c1.y, c1.z, c1.w};
#pragma unroll
                for (int u = 0; u < 16; ++u) {
                    const unsigned w_ = q[u >> 1];
                    d[u] = __uint_as_float((u & 1) ? (w_ & 0xffff0000u) : (w_ << 16));
                }
                c0 = *(const uint4*)(Dbase + off);   // band-32 overshoot in-bounds
                c1 = *(const uint4*)(Dbase + off + 16);
                off += 32;
            } else {
                // Static extraction: d[15]=B0.hi; d[14..7]=B1 lo/hi ascending;
                // d[6..0]=B2 lo/hi ascending (verified index algebra, r18 base).
                const unsigned qb[8] = {B1.x, B1.y, B1.z, B1.w, B2.x, B2.y, B2.z, B2.w};
                d[15] = __uint_as_float(B0 & 0xffff0000u);
#pragma unroll
                for (int u = 7; u <= 14; ++u) {
                    const unsigned w_ = qb[(14 - u) >> 1];
                    d[u] = __uint_as_float(((14 - u) & 1) ? (w_ & 0xffff0000u) : (w_ << 16));
                }
#pragma unroll
                for (int u = 0; u <= 6; ++u) {
                    const unsigned w_ = qb[4 + ((6 - u) >> 1)];
                    d[u] = __uint_as_float(((6 - u) & 1) ? (w_ & 0xffff0000u) : (w_ << 16));
                }
                // Prefetch band k+1 (min a0 over all waves/bands = 488 >= 0).
                B0 = *(const unsigned*)(Dp + a0 + 6);
                B1 = *(const uint4*)(Dp + a0 + 8);
                B2 = *(const uint4*)(Dp + a0 + 16);
                a0 -= 16;
            }
            __builtin_amdgcn_sched_barrier(0);       // pin loads before compute

            if (k == k0 && haveup) {                 // window entry boundary
                const int m2 = 3 - m0 - m1;
                hband_prev = hnd[m2][wv - 1][15];
            }
            const float hband = haveup ? hnd[m1][wv - 1][lane & 15] : LARGE_F;
            float h[16];
#pragma unroll
            for (int u = 0; u < 16; ++u) {
                const float nvec = wave_shr1(cur, LARGE_F);
                const float hu = __int_as_float(__builtin_amdgcn_readlane(
                    __float_as_int((u == 0) ? hband_prev : hband),
                    (u == 0) ? 15 : (u - 1)));
                const float n  = (haveup && l0) ? hu : nvec;
                const float mn = fminf(fminf(cur, n), nw);
                const float mx = fmaxf(fmaxf(cur, n), nw);
                const float md = __builtin_amdgcn_fmed3f(cur, n, nw);
                const float sm = mn - fast_log2(1.f + fast_exp2(mn - md) + fast_exp2(mn - mx));
                const float newc = d[u] + sm;
                h[u] = newc;
                nw = n; cur = newc;
            }
            hband_prev = hband;
            if (k == 31) { r510 = h[14]; r511 = h[15]; }   // p=510, p=511
            if (lane == 63) {
                *(float4*)(&hnd[m0][wv][0])  = make_float4(h[0], h[1], h[2], h[3]);
                *(float4*)(&hnd[m0][wv][4])  = make_float4(h[4], h[5], h[6], h[7]);
                *(float4*)(&hnd[m0][wv][8])  = make_float4(h[8], h[9], h[10], h[11]);
                *(float4*)(&hnd[m0][wv][12]) = make_float4(h[12], h[13], h[14], h[15]);
            }
        }
        asm volatile("s_waitcnt lgkmcnt(0)" ::: "memory");
        __builtin_amdgcn_s_barrier();        // raw: vmcnt NOT drained
        m0 = (m0 == 2) ? 0 : m0 + 1;
        m1 = (m1 == 2) ? 0 : m1 + 1;
    }
    // exports: arrays [0]=Rf511 [1]=Rf510 [2]=Rb511 [3]=Rb510, each [batch][row]
    exps[((dir << 1) + 0) * EXPN + (batch << 9) + tid] = r511;
    exps[((dir << 1) + 1) * EXPN + (batch << 9) + tid] = r510;
}

// ---------------- Phase 3: combine. Every monotone path crosses diag 511 once
// (term1, D'-corrected) or jumps 510->512 (term2). Max-subtracted log2sumexp.
__global__ __launch_bounds__(512) void sdtw_combine(const unsigned short* __restrict__ Dws,
                                                    const float* __restrict__ exps,
                                                    float* __restrict__ out) {
    __shared__ float red[8];
    const int b = blockIdx.x, i = threadIdx.x;
    const int lane = i & 63, wv = i >> 6;

    const float rf511 = exps[0 * EXPN + (b << 9) + i];
    const float rf510 = exps[1 * EXPN + (b << 9) + i];
    const float rb511 = exps[2 * EXPN + (b << 9) + (511 - i)];
    const float rb510 = (i < 511) ? exps[3 * EXPN + (b << 9) + (510 - i)] : 0.f;
    const unsigned short dsh = Dws[(size_t)b * PBATCH + (i << 9) + 511];  // D'(i,511-i)
    const float d511 = __uint_as_float((unsigned)dsh << 16);

    const float t1 = d511 - rf511 - rb511;                  // visit diag 511
    const float t2 = (i < 511) ? (-rf510 - rb510) : -LARGE_F;  // jump 510->512

    float m = fmaxf(t1, t2);
#pragma unroll
    for (int s_ = 1; s_ < 64; s_ <<= 1) m = fmaxf(m, __shfl_xor(m, s_));
    if (lane == 0) red[wv] = m;
    __syncthreads();
    float M = red[0];
#pragma unroll
    for (int w_ = 1; w_ < 8; ++w_) M = fmaxf(M, red[w_]);
    __syncthreads();

    float s = fast_exp2(t1 - M) + ((i < 511) ? fast_exp2(t2 - M) : 0.f);
#pragma unroll
    for (int s_ = 1; s_ < 64; s_ <<= 1) s += __shfl_xor(s, s_);
    if (lane == 0) red[wv] = s;
    __syncthreads();
    if (i == 0) {
        float S = red[0];
#pragma unroll
        for (int w_ = 1; w_ < 8; ++w_) S += red[w_];
        out[b] = -(M + fast_log2(S)) * LN2_F;
    }
}

// ---------------- Fallback (only if ws too small): fused, correct, slow.
__global__ __launch_bounds__(512) void sdtw_fused_naive(const float* __restrict__ x,
                                                        const float* __restrict__ y,
                                                        float* __restrict__ out) {
    __shared__ float rbuf[3][NN];
    __shared__ float y2s[MM];
    const int b = blockIdx.x;
    const int i = threadIdx.x;

    const float* xrow  = x + ((size_t)b * NN + i) * KK;
    const float* ybase = y + (size_t)b * MM * KK;

    float xr[KK];
    float x2 = 0.f;
#pragma unroll
    for (int k = 0; k < KK; k += 4) {
        const float4 v = *(const float4*)(xrow + k);
        xr[k] = v.x; xr[k + 1] = v.y; xr[k + 2] = v.z; xr[k + 3] = v.w;
        x2 = fmaf(v.x, v.x, fmaf(v.y, v.y, fmaf(v.z, v.z, fmaf(v.w, v.w, x2))));
    }
    {
        const float* yrow = ybase + (size_t)i * KK;
        float s = 0.f;
#pragma unroll
        for (int k = 0; k < KK; k += 4) {
            const float4 v = *(const float4*)(yrow + k);
            s = fmaf(v.x, v.x, s); s = fmaf(v.y, v.y, s);
            s = fmaf(v.z, v.z, s); s = fmaf(v.w, v.w, s);
        }
        y2s[i] = s;
    }
    rbuf[0][i] = LARGE_F;
    rbuf[1][i] = LARGE_F;
    rbuf[2][i] = LARGE_F;

    float* row_w  = rbuf[0];
    float* row_p  = rbuf[2];
    float* row_p2 = rbuf[1];
    __syncthreads();

    float cur = LARGE_F;
    for (int p = 0; p < NN + MM - 1; ++p) {
        const int j0 = p - i;
        const bool valid = (j0 >= 0) && (j0 < MM);
        float dg = 0.f;
        if (valid) {
            const float* yrow = ybase + (size_t)j0 * KK;
            float dot = 0.f;
#pragma unroll
            for (int k = 0; k < KK; k += 4) {
                const float4 v = *(const float4*)(yrow + k);
                dot = fmaf(xr[k], v.x, dot);
                dot = fmaf(xr[k + 1], v.y, dot);
                dot = fmaf(xr[k + 2], v.z, dot);
                dot = fmaf(xr[k + 3], v.w, dot);
            }
            dg = x2 + y2s[j0] - 2.f * dot;
        }
        const float r_w  = row_p[i];
        const float r_n  = (i > 0) ? row_p[i - 1] : LARGE_F;
        const float r_nw = (i > 0) ? row_p2[i - 1] : ((p == 0) ? 0.f : LARGE_F);

        const float m = fminf(fminf(r_nw, r_n), r_w);
        const float s = __expf(m - r_nw) + __expf(m - r_n) + __expf(m - r_w);
        const float softmin = m - __logf(s);

        cur = valid ? (dg + softmin) : LARGE_F;
        row_w[i] = cur;
        __syncthreads();

        float* tmp = row_w;
        row_w = row_p2; row_p2 = row_p; row_p = tmp;
    }
    if (i == NN - 1) out[b] = cur;
}

extern "C" void kernel_launch(void* const* d_in, const int* in_sizes, int n_in,
                              void* d_out, int out_size, void* d_ws, size_t ws_size,
                              hipStream_t stream) {
    const float* x = (const float*)d_in[0];
    const float* y = (const float*)d_in[1];
    float* out = (float*)d_out;

    if (ws_size >= NEED) {   // 68,288,512 B
        unsigned short* Dws = (unsigned short*)d_ws;
        float* exps = (float*)((char*)d_ws + EXP_OFF);
        sdtw_dist<<<dim3(2048), 256, 0, stream>>>(x, y, Dws);
        sdtw_dp_tri<<<dim3(256), 512, 0, stream>>>(Dws, exps);
        sdtw_combine<<<dim3(BB), 512, 0, stream>>>(Dws, exps, out);
    } else {
        sdtw_fused_naive<<<dim3(BB), 512, 0, stream>>>(x, y, out);
    }
}

// Round 20
// 93.480 us; speedup vs baseline: 1.2503x; 1.0206x over previous
//
#include <hip/hip_runtime.h>
#include <hip/hip_bf16.h>

#define LARGE_F 1e30f
#define LOG2E_F 1.4426950408889634f
#define LN2_F   0.6931471805599453f

constexpr int BB = 128;
constexpr int NN = 512;
constexpr int MM = 512;
constexpr int KK = 64;
// D layout: bf16, short index = 512*i + p (p = i+j). Row i spans [513i, 513i+511].
constexpr int PBATCH = 262656;              // shorts per batch (525,312 B)
constexpr int EXPN   = 65536;               // floats per export array (128*512)
constexpr size_t EXP_OFF = 67239936;        // bytes (= 128*PBATCH*2), 16B-aligned
constexpr size_t NEED = EXP_OFF + 4 * (size_t)EXPN * 4;   // 68,288,512 B

typedef __attribute__((ext_vector_type(8))) short short8;   // 8 bf16 (guide §3)
typedef __attribute__((ext_vector_type(4))) float f32x4;

// lane i <- lane i-1 via DPP wave_shr:1 (VALU). Lane 0 receives `bound`.
__device__ __forceinline__ float wave_shr1(float v, float bound) {
    const int r = __builtin_amdgcn_update_dpp(__float_as_int(bound), __float_as_int(v),
                                              0x138, 0xf, 0xf, false);
    return __int_as_float(r);
}

__device__ __forceinline__ unsigned pack_bf16(float a, float b) {
    __hip_bfloat16 ha = __float2bfloat16(a);
    __hip_bfloat16 hb = __float2bfloat16(b);
    return (unsigned)*(unsigned short*)&ha | ((unsigned)*(unsigned short*)&hb << 16);
}

// Raw-instruction transcendentals (v_exp_f32 / v_log_f32, ~1 ulp).
__device__ __forceinline__ float fast_exp2(float x) { return __builtin_amdgcn_exp2f(x); }
__device__ __forceinline__ float fast_log2(float x) { return __builtin_amdgcn_logf(x); }

// ---------------- Phase 1 (MFMA): D[i][p] = ||x_i - y_j||^2 * log2e (bf16).
// (unchanged; proven rounds 14-19)
__global__ __launch_bounds__(256, 2) void sdtw_dist(const float* __restrict__ x,
                                                    const float* __restrict__ y,
                                                    unsigned short* __restrict__ Dws) {
    __shared__ __align__(16) unsigned short xbf[128][88];
    __shared__ __align__(16) unsigned short ybf[128][88];
    __shared__ float x2s[128], y2s[128];
    __shared__ float xpart[128][2], ypart[128][2];
    unsigned short (*dt)[132] = (unsigned short (*)[132])(&xbf[0][0]);

    const int bid  = blockIdx.x;
    const int xcd  = bid & 7, sidx = bid >> 3;
    const int g    = sidx >> 4, tile = sidx & 15;
    const int b    = xcd + (g << 3);
    const int ti   = (tile >> 2) << 7, tj = (tile & 3) << 7;
    const int t    = threadIdx.x;

    const float* xb = x + ((size_t)b * NN + ti) * KK;
    const float* yb = y + ((size_t)b * MM + tj) * KK;

    {
        const int r = t >> 1, h = t & 1;
        const float* xr = xb + r * KK + h * 32;
        const float* yr = yb + r * KK + h * 32;
        float sx = 0.f, sy = 0.f;
        unsigned xu[16], yu[16];
#pragma unroll
        for (int q = 0; q < 8; ++q) {
            const float4 v = *(const float4*)(xr + 4 * q);
            sx = fmaf(v.x, v.x, fmaf(v.y, v.y, fmaf(v.z, v.z, fmaf(v.w, v.w, sx))));
            xu[2 * q]     = pack_bf16(v.x, v.y);
            xu[2 * q + 1] = pack_bf16(v.z, v.w);
            const float4 u = *(const float4*)(yr + 4 * q);
            sy = fmaf(u.x, u.x, fmaf(u.y, u.y, fmaf(u.z, u.z, fmaf(u.w, u.w, sy))));
            yu[2 * q]     = pack_bf16(u.x, u.y);
            yu[2 * q + 1] = pack_bf16(u.z, u.w);
        }
#pragma unroll
        for (int q = 0; q < 4; ++q) {
            *(uint4*)(&xbf[r][h * 32 + q * 8]) = make_uint4(xu[4*q], xu[4*q+1], xu[4*q+2], xu[4*q+3]);
            *(uint4*)(&ybf[r][h * 32 + q * 8]) = make_uint4(yu[4*q], yu[4*q+1], yu[4*q+2], yu[4*q+3]);
        }
        xpart[r][h] = sx; ypart[r][h] = sy;
    }
    __syncthreads();
    if (t < 128) x2s[t] = xpart[t][0] + xpart[t][1];
    else         y2s[t - 128] = ypart[t - 128][0] + ypart[t - 128][1];
    __syncthreads();

    const int w    = t >> 6, lane = t & 63;
    const int wr   = (w >> 1) << 6, wc = (w & 1) << 6;
    const int fr   = lane & 15;
    const int fk   = (lane >> 4) << 3;

    f32x4 acc[4][4] = {};
#pragma unroll
    for (int c = 0; c < 2; ++c) {
        short8 A[4], Bf[4];
#pragma unroll
        for (int a = 0; a < 4; ++a)
            A[a] = *(const short8*)(&xbf[wr + (a << 4) + fr][(c << 5) + fk]);
#pragma unroll
        for (int bb = 0; bb < 4; ++bb)
            Bf[bb] = *(const short8*)(&ybf[wc + (bb << 4) + fr][(c << 5) + fk]);
#pragma unroll
        for (int a = 0; a < 4; ++a)
#pragma unroll
            for (int bb = 0; bb < 4; ++bb)
                acc[a][bb] = __builtin_amdgcn_mfma_f32_16x16x32_bf16(
                    A[a], Bf[bb], acc[a][bb], 0, 0, 0);
    }
    __syncthreads();

    {
        const int er = (lane >> 4) << 2;
        const int ec = lane & 15;
#pragma unroll
        for (int a = 0; a < 4; ++a) {
#pragma unroll
            for (int bb = 0; bb < 4; ++bb) {
                const int lcol = wc + (bb << 4) + ec;
                const float yy = y2s[lcol];
#pragma unroll
                for (int reg = 0; reg < 4; ++reg) {
                    const int lrow = wr + (a << 4) + er + reg;
                    const float d = (x2s[lrow] + yy - 2.f * acc[a][bb][reg]) * LOG2E_F;
                    __hip_bfloat16 hh = __float2bfloat16(d);
                    dt[lrow][lcol] = *(unsigned short*)&hh;
                }
            }
        }
    }
    __syncthreads();

    {
        unsigned short* Dg = Dws + (size_t)b * PBATCH;
#pragma unroll 4
        for (int r = w; r < 128; r += 4) {
            const int gi = ti + r;
            const int base = 512 * gi + (gi + tj);
            Dg[base + lane]      = dt[r][lane];
            Dg[base + lane + 64] = dt[r][lane + 64];
        }
    }
}

// ---------------- Phase 2: TRIANGLE DP (fwd & bwd), 256 blocks = 2 per batch.
// Round-20: BAND SIZE 32 (was 16) -> epochs 39 -> 23. Issue is only ~1/3 of
// the r19 wall; the rest is per-epoch serial overhead (post-barrier hband
// latency, readlanes, export flush, barrier turnaround) -- paid per epoch, so
// cut epoch count, accepting +18% critical-path steps (736 vs 624).
// Window [2wv, 15]; handoff hnd[3][8][32]; exports chunked every 8 steps.
__global__ __launch_bounds__(512, 1) void sdtw_dp_tri(const unsigned short* __restrict__ Dws,
                                                      float* __restrict__ exps) {
    __shared__ __align__(16) float hnd[3][8][32];   // 3072 B
    const int blk   = blockIdx.x;
    const int batch = blk >> 1, dir = blk & 1;
    const int tid   = threadIdx.x;       // row (in this direction's coords)
    const int lane  = tid & 63;
    const int wv    = tid >> 6;
    const int k0    = wv << 1;           // window start band (bands of 32 diags)

    ((float*)hnd)[tid] = LARGE_F;
    if (tid < 256) ((float*)hnd)[512 + tid] = LARGE_F;
    __syncthreads();

    const unsigned short* Dp = Dws + (size_t)batch * PBATCH;
    const char* Dbase = (const char*)Dp;

    float cur = LARGE_F;                     // R_{p-1}[tid]
    float nw  = (tid == 0) ? 0.f : LARGE_F;  // corner (0,0)
    float hband_prev = LARGE_F;
    const bool haveup = (wv > 0);
    const bool l0     = (lane == 0);
    float r510 = LARGE_F, r511 = LARGE_F;

    // Prologue: load band k0 (64 B per thread per band).
    unsigned off = (unsigned)tid * 1024u + ((unsigned)k0 << 6);
    uint4 c0, c1, c2, c3;        // fwd band regs (shorts off..off+63)
    unsigned B0; uint4 B1, B2, B3, B4;   // bwd: shorts a0+6..7, +8..15, ..., +32..39
    int a0 = 0;
    if (dir == 0) {
        c0 = *(const uint4*)(Dbase + off);
        c1 = *(const uint4*)(Dbase + off + 16);
        c2 = *(const uint4*)(Dbase + off + 32);
        c3 = *(const uint4*)(Dbase + off + 48);
        off += 64;
    } else {
        // bwd thread tid owns orig row r=511-tid; band k needs shorts
        // [s0, s0+31], s0 = 512r + 991 - 32k (d[u] = shorts[s0+31-u]).
        // s0 == 7 (mod 8): a0 = s0-7 is 16B-aligned. Max read a0+39 = 262,655
        // < PBATCH; min prefetch a0 = 472 >= 0.
        a0 = 512 * (511 - tid) + 984 - (k0 << 5);
        B0 = *(const unsigned*)(Dp + a0 + 6);
        B1 = *(const uint4*)(Dp + a0 + 8);
        B2 = *(const uint4*)(Dp + a0 + 16);
        B3 = *(const uint4*)(Dp + a0 + 24);
        B4 = *(const uint4*)(Dp + a0 + 32);
        a0 -= 32;
    }

    int m0 = 0, m1 = 2;                      // e%3, (e-1)%3
#pragma unroll 1
    for (int e = 0; e < 23; ++e) {
        const int k = e - wv;
        if (k >= k0 && k <= 15) {
            float d[32];
            if (dir == 0) {
                const unsigned q[16] = {c0.x, c0.y, c0.z, c0.w, c1.x, c1.y, c1.z, c1.w,
                                        c2.x, c2.y, c2.z, c2.w, c3.x, c3.y, c3.z, c3.w};
#pragma unroll
                for (int u = 0; u < 32; ++u) {
                    const unsigned w_ = q[u >> 1];
                    d[u] = __uint_as_float((u & 1) ? (w_ & 0xffff0000u) : (w_ << 16));
                }
                c0 = *(const uint4*)(Dbase + off);   // band-16 overshoot in-bounds
                c1 = *(const uint4*)(Dbase + off + 16);
                c2 = *(const uint4*)(Dbase + off + 32);
                c3 = *(const uint4*)(Dbase + off + 48);
                off += 64;
            } else {
                // d[31]=B0.hi; d[u] (u<=30) = qb[(30-u)>>1], u odd -> hi.
                const unsigned qb[16] = {B1.x, B1.y, B1.z, B1.w, B2.x, B2.y, B2.z, B2.w,
                                         B3.x, B3.y, B3.z, B3.w, B4.x, B4.y, B4.z, B4.w};
                d[31] = __uint_as_float(B0 & 0xffff0000u);
#pragma unroll
                for (int u = 0; u <= 30; ++u) {
                    const unsigned w_ = qb[(30 - u) >> 1];
                    d[u] = __uint_as_float((u & 1) ? (w_ & 0xffff0000u) : (w_ << 16));
                }
                B0 = *(const unsigned*)(Dp + a0 + 6);   // prefetch band k+1
                B1 = *(const uint4*)(Dp + a0 + 8);
                B2 = *(const uint4*)(Dp + a0 + 16);
                B3 = *(const uint4*)(Dp + a0 + 24);
                B4 = *(const uint4*)(Dp + a0 + 32);
                a0 -= 32;
            }
            __builtin_amdgcn_sched_barrier(0);       // pin loads before compute

            if (k == k0 && haveup) {                 // window entry boundary
                const int m2 = 3 - m0 - m1;
                hband_prev = hnd[m2][wv - 1][31];
            }
            const float hband = haveup ? hnd[m1][wv - 1][lane & 31] : LARGE_F;
            float hq[8];
            float l30 = LARGE_F, l31 = LARGE_F;
#pragma unroll
            for (int u = 0; u < 32; ++u) {
                const float nvec = wave_shr1(cur, LARGE_F);
                const float hu = __int_as_float(__builtin_amdgcn_readlane(
                    __float_as_int((u == 0) ? hband_prev : hband),
                    (u == 0) ? 31 : (u - 1)));
                const float n  = (haveup && l0) ? hu : nvec;
                const float mn = fminf(fminf(cur, n), nw);
                const float mx = fmaxf(fmaxf(cur, n), nw);
                const float md = __builtin_amdgcn_fmed3f(cur, n, nw);
                const float sm = mn - fast_log2(1.f + fast_exp2(mn - md) + fast_exp2(mn - mx));
                const float newc = d[u] + sm;
                hq[u & 7] = newc;
                if (u == 30) l30 = newc;
                if (u == 31) l31 = newc;
                nw = n; cur = newc;
                if ((u & 7) == 7 && lane == 63) {    // chunked export (8 steps)
                    *(float4*)(&hnd[m0][wv][u - 7]) = make_float4(hq[0], hq[1], hq[2], hq[3]);
                    *(float4*)(&hnd[m0][wv][u - 3]) = make_float4(hq[4], hq[5], hq[6], hq[7]);
                }
            }
            hband_prev = hband;
            if (k == 15) { r510 = l30; r511 = l31; }   // p=510, p=511
        }
        asm volatile("s_waitcnt lgkmcnt(0)" ::: "memory");
        __builtin_amdgcn_s_barrier();        // raw: vmcnt NOT drained
        m0 = (m0 == 2) ? 0 : m0 + 1;
        m1 = (m1 == 2) ? 0 : m1 + 1;
    }
    // exports: arrays [0]=Rf511 [1]=Rf510 [2]=Rb511 [3]=Rb510, each [batch][row]
    exps[((dir << 1) + 0) * EXPN + (batch << 9) + tid] = r511;
    exps[((dir << 1) + 1) * EXPN + (batch << 9) + tid] = r510;
}

// ---------------- Phase 3: combine. Every monotone path crosses diag 511 once
// (term1, D'-corrected) or jumps 510->512 (term2). Max-subtracted log2sumexp.
__global__ __launch_bounds__(512) void sdtw_combine(const unsigned short* __restrict__ Dws,
                                                    const float* __restrict__ exps,
                                                    float* __restrict__ out) {
    __shared__ float red[8];
    const int b = blockIdx.x, i = threadIdx.x;
    const int lane = i & 63, wv = i >> 6;

    const float rf511 = exps[0 * EXPN + (b << 9) + i];
    const float rf510 = exps[1 * EXPN + (b << 9) + i];
    const float rb511 = exps[2 * EXPN + (b << 9) + (511 - i)];
    const float rb510 = (i < 511) ? exps[3 * EXPN + (b << 9) + (510 - i)] : 0.f;
    const unsigned short dsh = Dws[(size_t)b * PBATCH + (i << 9) + 511];  // D'(i,511-i)
    const float d511 = __uint_as_float((unsigned)dsh << 16);

    const float t1 = d511 - rf511 - rb511;                  // visit diag 511
    const float t2 = (i < 511) ? (-rf510 - rb510) : -LARGE_F;  // jump 510->512

    float m = fmaxf(t1, t2);
#pragma unroll
    for (int s_ = 1; s_ < 64; s_ <<= 1) m = fmaxf(m, __shfl_xor(m, s_));
    if (lane == 0) red[wv] = m;
    __syncthreads();
    float M = red[0];
#pragma unroll
    for (int w_ = 1; w_ < 8; ++w_) M = fmaxf(M, red[w_]);
    __syncthreads();

    float s = fast_exp2(t1 - M) + ((i < 511) ? fast_exp2(t2 - M) : 0.f);
#pragma unroll
    for (int s_ = 1; s_ < 64; s_ <<= 1) s += __shfl_xor(s, s_);
    if (lane == 0) red[wv] = s;
    __syncthreads();
    if (i == 0) {
        float S = red[0];
#pragma unroll
        for (int w_ = 1; w_ < 8; ++w_) S += red[w_];
        out[b] = -(M + fast_log2(S)) * LN2_F;
    }
}

// ---------------- Fallback (only if ws too small): fused, correct, slow.
__global__ __launch_bounds__(512) void sdtw_fused_naive(const float* __restrict__ x,
                                                        const float* __restrict__ y,
                                                        float* __restrict__ out) {
    __shared__ float rbuf[3][NN];
    __shared__ float y2s[MM];
    const int b = blockIdx.x;
    const int i = threadIdx.x;

    const float* xrow  = x + ((size_t)b * NN + i) * KK;
    const float* ybase = y + (size_t)b * MM * KK;

    float xr[KK];
    float x2 = 0.f;
#pragma unroll
    for (int k = 0; k < KK; k += 4) {
        const float4 v = *(const float4*)(xrow + k);
        xr[k] = v.x; xr[k + 1] = v.y; xr[k + 2] = v.z; xr[k + 3] = v.w;
        x2 = fmaf(v.x, v.x, fmaf(v.y, v.y, fmaf(v.z, v.z, fmaf(v.w, v.w, x2))));
    }
    {
        const float* yrow = ybase + (size_t)i * KK;
        float s = 0.f;
#pragma unroll
        for (int k = 0; k < KK; k += 4) {
            const float4 v = *(const float4*)(yrow + k);
            s = fmaf(v.x, v.x, s); s = fmaf(v.y, v.y, s);
            s = fmaf(v.z, v.z, s); s = fmaf(v.w, v.w, s);
        }
        y2s[i] = s;
    }
    rbuf[0][i] = LARGE_F;
    rbuf[1][i] = LARGE_F;
    rbuf[2][i] = LARGE_F;

    float* row_w  = rbuf[0];
    float* row_p  = rbuf[2];
    float* row_p2 = rbuf[1];
    __syncthreads();

    float cur = LARGE_F;
    for (int p = 0; p < NN + MM - 1; ++p) {
        const int j0 = p - i;
        const bool valid = (j0 >= 0) && (j0 < MM);
        float dg = 0.f;
        if (valid) {
            const float* yrow = ybase + (size_t)j0 * KK;
            float dot = 0.f;
#pragma unroll
            for (int k = 0; k < KK; k += 4) {
                const float4 v = *(const float4*)(yrow + k);
                dot = fmaf(xr[k], v.x, dot);
                dot = fmaf(xr[k + 1], v.y, dot);
                dot = fmaf(xr[k + 2], v.z, dot);
                dot = fmaf(xr[k + 3], v.w, dot);
            }
            dg = x2 + y2s[j0] - 2.f * dot;
        }
        const float r_w  = row_p[i];
        const float r_n  = (i > 0) ? row_p[i - 1] : LARGE_F;
        const float r_nw = (i > 0) ? row_p2[i - 1] : ((p == 0) ? 0.f : LARGE_F);

        const float m = fminf(fminf(r_nw, r_n), r_w);
        const float s = __expf(m - r_nw) + __expf(m - r_n) + __expf(m - r_w);
        const float softmin = m - __logf(s);

        cur = valid ? (dg + softmin) : LARGE_F;
        row_w[i] = cur;
        __syncthreads();

        float* tmp = row_w;
        row_w = row_p2; row_p2 = row_p; row_p = tmp;
    }
    if (i == NN - 1) out[b] = cur;
}

extern "C" void kernel_launch(void* const* d_in, const int* in_sizes, int n_in,
                              void* d_out, int out_size, void* d_ws, size_t ws_size,
                              hipStream_t stream) {
    const float* x = (const float*)d_in[0];
    const float* y = (const float*)d_in[1];
    float* out = (float*)d_out;

    if (ws_size >= NEED) {   // 68,288,512 B
        unsigned short* Dws = (unsigned short*)d_ws;
        float* exps = (float*)((char*)d_ws + EXP_OFF);
        sdtw_dist<<<dim3(2048), 256, 0, stream>>>(x, y, Dws);
        sdtw_dp_tri<<<dim3(256), 512, 0, stream>>>(Dws, exps);
        sdtw_combine<<<dim3(BB), 512, 0, stream>>>(Dws, exps, out);
    } else {
        sdtw_fused_naive<<<dim3(BB), 512, 0, stream>>>(x, y, out);
    }
}